// Round 20
// baseline (50.684 us; speedup 1.0000x reference)
//
#include <hip/hip_runtime.h>
#include <math.h>

#define T_LEN 1024
#define PRED_LEN 256
#define OUT_T (T_LEN + PRED_LEN)
#define DM 256
#define KSEL 32
#define RTAU 1e-4f

#define PADH(i) ((i) + ((i) >> 4))    // float2 arrays
#define C512F  0.012271846303085130f  // 2*pi/512
#define C1024F 0.006135923151542565f  // 2*pi/1024

#define R2F 0.70710678118654752440f
// W8[e] = exp(-2*pi*i*e/8)
__device__ __constant__ float W8RF[8] = { 1.f,  R2F, 0.f, -R2F, -1.f, -R2F, 0.f,  R2F };
__device__ __constant__ float W8IF[8] = { 0.f, -R2F, -1.f, -R2F, 0.f,  R2F, 1.f,  R2F };

// W16 in fp64 (refinement rotation steps): exp(-2*pi*i*e/16)
#define C1_ 0.92387953251128675613
#define C2_ 0.70710678118654752440
#define C3_ 0.38268343236508977173
__device__ __constant__ double W16R_[16] = {
    1.0,  C1_,  C2_,  C3_, 0.0, -C3_, -C2_, -C1_,
   -1.0, -C1_, -C2_, -C3_, 0.0,  C3_,  C2_,  C1_ };
__device__ __constant__ double W16I_[16] = {
    0.0, -C3_, -C2_, -C1_, -1.0, -C1_, -C2_, -C3_,
    0.0,  C3_,  C2_,  C1_,  1.0,  C1_,  C2_,  C3_ };

// ---- masked inverse-prep value for FFT2: conj(G[k]) from X table + selection bits ----
__device__ __forceinline__ float2 gval(const float2* __restrict__ xt,
                                       const unsigned* __restrict__ selw,
                                       const float2* __restrict__ twH, int k) {
    if (k == 0) return float2{ 0.f, 0.f };
    const int kk = 512 - k;                      // 1..511
    const bool sk  = (selw[k  >> 5] >> (k  & 31)) & 1u;
    const bool skk = (selw[kk >> 5] >> (kk & 31)) & 1u;
    float2 Yk = xt[PADH(k)];  if (!sk)  Yk = float2{ 0.f, 0.f };
    float2 Ym = xt[PADH(kk)]; if (!skk) Ym = float2{ 0.f, 0.f };
    float Epr = 0.5f * (Yk.x + Ym.x), Epi = 0.5f * (Yk.y - Ym.y);
    float Dpr = 0.5f * (Yk.x - Ym.x), Dpi = 0.5f * (Yk.y + Ym.y);
    float2 twc = twH[PADH(k)];
    float wr = twc.x, wi = -twc.y;               // conj(W1024^k)
    float Opr = Dpr * wr - Dpi * wi;
    float Opi = Dpr * wi + Dpi * wr;
    return float2{ Epr - Opi, -(Epi + Opr) };    // conj(E' + i O')
}

// ---- 512-pt FFT core (8 x 64 four-step). thread (w, lane): X[k], k = (2w+q) + 8*rev6(lane)
__device__ __forceinline__ void fft512(const float2* __restrict__ zin,
                                       const float2* __restrict__ tw512,
                                       int lane, int w, float* ar, float* ai) {
    float2 zv[8];
#pragma unroll
    for (int n1 = 0; n1 < 8; ++n1) zv[n1] = zin[PADH(lane + (n1 << 6))];
#pragma unroll
    for (int q = 0; q < 2; ++q) {
        const int k1 = (w << 1) | q;
        float cr = 0.f, ci = 0.f;
#pragma unroll
        for (int n1 = 0; n1 < 8; ++n1) {
            int e = (k1 * n1) & 7;
            float wr = W8RF[e], wi = W8IF[e];
            cr += zv[n1].x * wr - zv[n1].y * wi;
            ci += zv[n1].x * wi + zv[n1].y * wr;
        }
        float2 tw = tw512[PADH(lane * k1)];      // <= 441
        ar[q] = cr * tw.x - ci * tw.y;
        ai[q] = cr * tw.y + ci * tw.x;
    }
#pragma unroll
    for (int s = 0; s < 6; ++s) {
        const int half = 32 >> s;
        const int e = (lane & (half - 1)) << s;
        float2 tw = tw512[PADH(e << 3)];         // W64^e = W512^(8e)
        const bool up = (lane & half) != 0;
#pragma unroll
        for (int q = 0; q < 2; ++q) {
            float orr = __shfl_xor(ar[q], half);
            float oii = __shfl_xor(ai[q], half);
            float sr = ar[q] + orr, si = ai[q] + oii;
            float dr = orr - ar[q], di = oii - ai[q];
            ar[q] = up ? (dr * tw.x - di * tw.y) : sr;
            ai[q] = up ? (dr * tw.y + di * tw.x) : si;
        }
    }
}

// ---- same core, inputs generated via gval (masked inverse prep) ----
__device__ __forceinline__ void fft512_g(const float2* __restrict__ xt,
                                         const unsigned* __restrict__ selw,
                                         const float2* __restrict__ twH,
                                         const float2* __restrict__ tw512,
                                         int lane, int w, float* ar, float* ai) {
    float2 zv[8];
#pragma unroll
    for (int n1 = 0; n1 < 8; ++n1) zv[n1] = gval(xt, selw, twH, lane + (n1 << 6));
#pragma unroll
    for (int q = 0; q < 2; ++q) {
        const int k1 = (w << 1) | q;
        float cr = 0.f, ci = 0.f;
#pragma unroll
        for (int n1 = 0; n1 < 8; ++n1) {
            int e = (k1 * n1) & 7;
            float wr = W8RF[e], wi = W8IF[e];
            cr += zv[n1].x * wr - zv[n1].y * wi;
            ci += zv[n1].x * wi + zv[n1].y * wr;
        }
        float2 tw = tw512[PADH(lane * k1)];
        ar[q] = cr * tw.x - ci * tw.y;
        ai[q] = cr * tw.y + ci * tw.x;
    }
#pragma unroll
    for (int s = 0; s < 6; ++s) {
        const int half = 32 >> s;
        const int e = (lane & (half - 1)) << s;
        float2 tw = tw512[PADH(e << 3)];
        const bool up = (lane & half) != 0;
#pragma unroll
        for (int q = 0; q < 2; ++q) {
            float orr = __shfl_xor(ar[q], half);
            float oii = __shfl_xor(ai[q], half);
            float sr = ar[q] + orr, si = ai[q] + oii;
            float dr = orr - ar[q], di = oii - ai[q];
            ar[q] = up ? (dr * tw.x - di * tw.y) : sr;
            ai[q] = up ? (dr * tw.y + di * tw.x) : si;
        }
    }
}

// ---------------- Per-column fused kernel ----------------
// grid = 2048 blocks (one real column each), block = 256 threads = 4 waves.
// LDS ~18.4 KB -> 8 blocks/CU; natural VGPR (no min-wave clamp) -> up to 32 waves/CU.
__global__ void __launch_bounds__(256)
fl_fused_kernel(const float* __restrict__ x, float* __restrict__ out) {
    __shared__ float2 tw512[PADH(511) + 1];   // W512^e
    __shared__ float2 twH[PADH(511) + 1];     // W1024^e (untangle / re-tangle)
    __shared__ float2 arrA[PADH(511) + 1];    // z input -> X[k] table
    __shared__ float2 arrB[PADH(511) + 1];    // Z spectrum
    __shared__ int hist[256];
    __shared__ unsigned selw[16];             // 512-bit selection set

    const int tid  = threadIdx.x;
    const int lane = tid & 63;
    const int w    = tid >> 6;

    const int bid = blockIdx.x;
    const int b   = bid & 7;                  // batch == XCD
    const int d   = bid >> 3;                 // column; 16 same-line columns share an XCD

    // in-block twiddles (2 entries per table per thread)
    for (int j = 0; j < 2; ++j) {
        int e = tid + (j << 8);
        float sn, cs;
        __sincosf((float)e * C512F, &sn, &cs);
        tw512[PADH(e)] = float2{ cs, -sn };
        __sincosf((float)e * C1024F, &sn, &cs);
        twH[PADH(e)] = float2{ cs, -sn };
    }
    // stage column as z[n] = x[2n] + i*x[2n+1] (scalar loads, scalar LDS writes)
    {
        const float* xc = x + (((size_t)b << 10) << 8) + d;
        float* zf = (float*)arrA;
        for (int j = 0; j < 4; ++j) {
            int t = tid + (j << 8);
            float xv = xc[(size_t)t << 8];
            zf[2 * PADH(t >> 1) + (t & 1)] = xv;
        }
    }
    if (tid < 16) selw[tid] = 0u;
    __syncthreads();                                   // barrier 1

    // ---- FFT1: Z = FFT512(z)
    float ar[2], ai[2];
    fft512(arrA, tw512, lane, w, ar, ai);
    const int krev = (int)(__brev((unsigned)lane) >> 26);
#pragma unroll
    for (int q = 0; q < 2; ++q) {
        int k = ((w << 1) | q) + (krev << 3);
        arrB[PADH(k)] = float2{ ar[q], ai[q] };
    }
    __syncthreads();                                   // barrier 2

    // ---- divergent: wave 0 does top-k; waves 1,2 build X[k] table in arrA
    if (tid < 64) {
        // magnitudes via on-the-fly untangle
        float v[8]; int hiw[8];
#pragma unroll
        for (int q = 0; q < 8; ++q) {
            int m = (q << 6) | lane;
            int n = (512 - m) & 511;
            float2 Zk = arrB[PADH(m & 511)];
            float2 Zm = arrB[PADH(n)];
            float Er = 0.5f * (Zk.x + Zm.x), Ei = 0.5f * (Zk.y - Zm.y);
            float Dr = 0.5f * (Zk.x - Zm.x), Di = 0.5f * (Zk.y + Zm.y);
            float Or = Di, Oi = -Dr;                   // O = -i*D
            float2 tw = twH[PADH(m)];
            float Xr = Er + Or * tw.x - Oi * tw.y;
            float Xi = Ei + Or * tw.y + Oi * tw.x;
            v[q] = Xr * Xr + Xi * Xi;
        }
        if (lane == 0) v[0] = -1.0f;   // exclude m=0; m=512 excluded by range
#pragma unroll
        for (int q = 0; q < 8; ++q) hiw[q] = __float_as_int(v[q]);

        int mx = hiw[0];
#pragma unroll
        for (int q = 1; q < 8; ++q) mx = max(mx, hiw[q]);
#pragma unroll
        for (int off = 1; off < 64; off <<= 1) mx = max(mx, __shfl_xor(mx, off));

        const int base = (mx >> 20) - 250;
        int idx[8];
#pragma unroll
        for (int q = 0; q < 8; ++q) {
            int t = (hiw[q] >> 20) - base;
            idx[q] = t < 0 ? 0 : t;
        }

        *reinterpret_cast<int4*>(&hist[lane << 2]) = int4{0, 0, 0, 0};
#pragma unroll
        for (int q = 0; q < 8; ++q) atomicAdd(&hist[idx[q]], 1);

        int4 cc = *reinterpret_cast<int4*>(&hist[lane << 2]);
        int s_local = cc.x + cc.y + cc.z + cc.w;

        int s = s_local;
#pragma unroll
        for (int off = 1; off < 64; off <<= 1) {
            int t = __shfl_down(s, off);
            if (lane + off < 64) s += t;
        }
        const int S_gt = s - s_local;
        const int A3 = S_gt;
        const int A2 = A3 + cc.w;
        const int A1 = A2 + cc.z;
        const int A0 = A1 + cc.y;

        int foundB = -1, foundR = 0;
        if (A0 < KSEL && A0 + cc.x >= KSEL) { foundB = (lane << 2) | 0; foundR = KSEL - A0; }
        if (A1 < KSEL && A1 + cc.y >= KSEL) { foundB = (lane << 2) | 1; foundR = KSEL - A1; }
        if (A2 < KSEL && A2 + cc.z >= KSEL) { foundB = (lane << 2) | 2; foundR = KSEL - A2; }
        if (A3 < KSEL && A3 + cc.w >= KSEL) { foundB = (lane << 2) | 3; foundR = KSEL - A3; }

        unsigned long long fm = __ballot(foundB >= 0);
        const int srcB = (int)(__ffsll((unsigned long long)fm) - 1);
        int B = __shfl(foundB, srcB);
        int r = __shfl(foundR, srcB);

        unsigned selmask = 0, candmask = 0;
#pragma unroll
        for (int q = 0; q < 8; ++q) {
            if (idx[q] > B) selmask |= (1u << q);
            else if (idx[q] == B) candmask |= (1u << q);
        }

        // second-level histogram on mantissa bits 12..19 (valid when B>0)
        if (r > 0 && B > 0) {
            *reinterpret_cast<int4*>(&hist[lane << 2]) = int4{0, 0, 0, 0};
            int idx2[8];
#pragma unroll
            for (int q = 0; q < 8; ++q) {
                idx2[q] = (hiw[q] >> 12) & 255;
                if ((candmask >> q) & 1u) atomicAdd(&hist[idx2[q]], 1);
            }
            int4 c2 = *reinterpret_cast<int4*>(&hist[lane << 2]);
            int s2l = c2.x + c2.y + c2.z + c2.w;
            int ss = s2l;
#pragma unroll
            for (int off = 1; off < 64; off <<= 1) {
                int t = __shfl_down(ss, off);
                if (lane + off < 64) ss += t;
            }
            const int G3 = ss - s2l;
            const int G2 = G3 + c2.w;
            const int G1 = G2 + c2.z;
            const int G0 = G1 + c2.y;
            int fB2 = -1, fR2 = 0;
            if (G0 < r && G0 + c2.x >= r) { fB2 = (lane << 2) | 0; fR2 = r - G0; }
            if (G1 < r && G1 + c2.y >= r) { fB2 = (lane << 2) | 1; fR2 = r - G1; }
            if (G2 < r && G2 + c2.z >= r) { fB2 = (lane << 2) | 2; fR2 = r - G2; }
            if (G3 < r && G3 + c2.w >= r) { fB2 = (lane << 2) | 3; fR2 = r - G3; }
            unsigned long long fm2 = __ballot(fB2 >= 0);
            const int src2 = (int)(__ffsll((unsigned long long)fm2) - 1);
            const int Bb = __shfl(fB2, src2);
            const int rr = __shfl(fR2, src2);
            unsigned newcand = 0;
#pragma unroll
            for (int q = 0; q < 8; ++q) {
                if ((candmask >> q) & 1u) {
                    if (idx2[q] > Bb) selmask |= (1u << q);
                    else if (idx2[q] == Bb) newcand |= (1u << q);
                }
            }
            candmask = newcand;
            r = rr;
        }

        for (int it = 0; it < r; ++it) {
            float bv = -2.0f; int bq = -1;
#pragma unroll
            for (int q = 0; q < 8; ++q) {
                bool cand = ((candmask >> q) & 1u) != 0;
                if (cand && v[q] > bv) { bv = v[q]; bq = q; }
            }
            int bi = (bq < 0) ? 0x7FFFFFFF : ((bq << 6) | lane);
#pragma unroll
            for (int off = 1; off < 64; off <<= 1) {
                float ov = __shfl_xor(bv, off);
                int   oi = __shfl_xor(bi, off);
                if (ov > bv || (ov == bv && oi < bi)) { bv = ov; bi = oi; }
            }
            if (bi != 0x7FFFFFFF && lane == (bi & 63)) {
                unsigned bit = 1u << (bi >> 6);
                selmask  |= bit;
                candmask &= ~bit;
            }
        }

        // fp64 refinement (rare): tableless rotation twiddles
        {
            float vminS = 3.0e38f, vmaxU = -3.0e38f;
#pragma unroll
            for (int q = 0; q < 8; ++q) {
                if ((selmask >> q) & 1u) vminS = fminf(vminS, v[q]);
                else                     vmaxU = fmaxf(vmaxU, v[q]);
            }
#pragma unroll
            for (int off = 1; off < 64; off <<= 1) {
                vminS = fminf(vminS, __shfl_xor(vminS, off));
                vmaxU = fmaxf(vmaxU, __shfl_xor(vmaxU, off));
            }
            const float tau = RTAU * vminS;
            if (vminS - vmaxU < tau) {
                const float lo = vmaxU - tau, hi = vminS + tau;
                unsigned candq = 0; int nAbove = 0;
#pragma unroll
                for (int q = 0; q < 8; ++q) {
                    bool inw = (v[q] >= lo) && (v[q] <= hi);
                    if (inw) candq |= (1u << q);
                    if (((selmask >> q) & 1u) && v[q] > hi) ++nAbove;
                }
#pragma unroll
                for (int off = 1; off < 64; off <<= 1) nAbove += __shfl_xor(nAbove, off);
                const int kneed = KSEL - nAbove;
                selmask &= ~candq;

                const float* xcol = x + (((size_t)b << 10) << 8) + d;
                double sV = -1.0; int sSrc = 0; int cnum = 0;
                for (int q = 0; q < 8; ++q) {
                    unsigned long long bal = __ballot((candq >> q) & 1u);
                    while (bal) {
                        int srcl = (int)(__ffsll(bal) - 1);
                        bal &= bal - 1;
                        int m = (q << 6) | srcl;
                        double th0 = (double)((m * lane) & 1023)
                                   * (-6.283185307179586476925286766559 / 1024.0);
                        double wr, wi;
                        { double s0, c0; sincos(th0, &s0, &c0); wr = c0; wi = s0; }
                        const double stR = W16R_[m & 15], stI = W16I_[m & 15];
                        double sr = 0.0, si = 0.0;
#pragma unroll
                        for (int u = 0; u < 16; ++u) {
                            int n = lane + (u << 6);
                            double xvd = (double)xcol[(size_t)n << 8];
                            sr = fma(xvd, wr, sr);
                            si = fma(xvd, wi, si);
                            double nwr = wr * stR - wi * stI;
                            double nwi = wr * stI + wi * stR;
                            wr = nwr; wi = nwi;
                        }
#pragma unroll
                        for (int off = 1; off < 64; off <<= 1) {
                            sr += __shfl_xor(sr, off);
                            si += __shfl_xor(si, off);
                        }
                        if (lane == cnum) { sV = sr * sr + si * si; sSrc = (q << 6) | srcl; }
                        ++cnum;
                        if (cnum >= 64) break;
                    }
                    if (cnum >= 64) break;
                }
                for (int it = 0; it < kneed; ++it) {
                    double bv = sV; int bl = lane;
#pragma unroll
                    for (int off = 1; off < 64; off <<= 1) {
                        double ov = __shfl_xor(bv, off);
                        int    ol = __shfl_xor(bl, off);
                        if (ov > bv || (ov == bv && ol < bl)) { bv = ov; bl = ol; }
                    }
                    int wsrc = __shfl(sSrc, bl);
                    if (lane == (wsrc & 63)) selmask |= 1u << (wsrc >> 6);
                    if (lane == bl) sV = -2.0;
                }
            }
        }

#pragma unroll
        for (int q = 0; q < 8; ++q) {
            if ((selmask >> q) & 1u) {
                int m = (q << 6) | lane;           // 1..511
                atomicOr(&selw[m >> 5], 1u << (m & 31));
            }
        }
    } else if (tid < 192) {
        // waves 1,2: untangle Z -> X[k] table in arrA (k = 0..511)
        const int t2 = tid - 64;                   // 0..127
#pragma unroll
        for (int j = 0; j < 4; ++j) {
            int k = t2 + (j << 7);                 // 0..511
            int n = (512 - k) & 511;
            float2 Zk = arrB[PADH(k)];
            float2 Zm = arrB[PADH(n)];
            float Er = 0.5f * (Zk.x + Zm.x), Ei = 0.5f * (Zk.y - Zm.y);
            float Dr = 0.5f * (Zk.x - Zm.x), Di = 0.5f * (Zk.y + Zm.y);
            float Or = Di, Oi = -Dr;
            float2 tw = twH[PADH(k)];
            arrA[PADH(k)] = float2{ Er + Or * tw.x - Oi * tw.y,
                                    Ei + Or * tw.y + Oi * tw.x };
        }
    }
    __syncthreads();                                   // barrier 3

    // ---- FFT2: C = FFT512(conj(G)) with masked G generated on the fly
    fft512_g(arrA, selw, twH, tw512, lane, w, ar, ai);

    // ---- write y[2n] = C.r/512, y[2n+1] = -C.i/512; duplicate t<256 to t+1024
    {
        const float S = 1.0f / 512.0f;
        float* ob = out + ((size_t)b * OUT_T) * DM + d;
#pragma unroll
        for (int q = 0; q < 2; ++q) {
            int n = ((w << 1) | q) + (krev << 3);
            float y0 = ar[q] * S;
            float y1 = -ai[q] * S;
            ob[(size_t)(2 * n)     << 8] = y0;
            ob[(size_t)(2 * n + 1) << 8] = y1;
            if (n < 128) {
                ob[(size_t)(2 * n + T_LEN)     << 8] = y0;
                ob[(size_t)(2 * n + 1 + T_LEN) << 8] = y1;
            }
        }
    }
}

extern "C" void kernel_launch(void* const* d_in, const int* in_sizes, int n_in,
                              void* d_out, int out_size, void* d_ws, size_t ws_size,
                              hipStream_t stream) {
    const float* x = (const float*)d_in[0];
    float* out = (float*)d_out;
    hipLaunchKernelGGL(fl_fused_kernel, dim3(2048), dim3(256), 0, stream, x, out);
}

// Round 21
// 35.863 us; speedup vs baseline: 1.4133x; 1.4133x over previous
//
#include <hip/hip_runtime.h>
#include <math.h>

#define T_LEN 1024
#define PRED_LEN 256
#define OUT_T (T_LEN + PRED_LEN)
#define DM 256
#define KSEL 32
#define RTAU 1e-4f

#define PAD16(i) ((i) + ((i) >> 4))   // float2 arrays
#define C1024F 0.006135923151542565f  // 2*pi/1024

// W16[e] = exp(-2*pi*i*e/16), fp32
__device__ __constant__ float W16RF[16] = {
    1.0f,  0.92387953f,  0.70710678f,  0.38268343f, 0.0f, -0.38268343f, -0.70710678f, -0.92387953f,
   -1.0f, -0.92387953f, -0.70710678f, -0.38268343f, 0.0f,  0.38268343f,  0.70710678f,  0.92387953f };
__device__ __constant__ float W16IF[16] = {
    0.0f, -0.38268343f, -0.70710678f, -0.92387953f, -1.0f, -0.92387953f, -0.70710678f, -0.38268343f,
    0.0f,  0.38268343f,  0.70710678f,  0.92387953f,  1.0f,  0.92387953f,  0.70710678f,  0.38268343f };

// W16 in fp64 (refinement rotation steps): exp(-2*pi*i*e/16)
#define C1_ 0.92387953251128675613
#define C2_ 0.70710678118654752440
#define C3_ 0.38268343236508977173
__device__ __constant__ double W16R_[16] = {
    1.0,  C1_,  C2_,  C3_, 0.0, -C3_, -C2_, -C1_,
   -1.0, -C1_, -C2_, -C3_, 0.0,  C3_,  C2_,  C1_ };
__device__ __constant__ double W16I_[16] = {
    0.0, -C3_, -C2_, -C1_, -1.0, -C1_, -C2_, -C3_,
    0.0,  C3_,  C2_,  C1_,  1.0,  C1_,  C2_,  C3_ };

// ---- masked-spectrum value for FFT2 (computed on the fly) ----
__device__ __forceinline__ float2 zval(const float2* __restrict__ xunp,
                                       const unsigned* __restrict__ selw, int k) {
    if (k == 0 || k == 512) return float2{ 0.f, 0.f };
    const int  fold = (k < 512) ? k : (1024 - k);
    const float sgn = (k < 512) ? 1.0f : -1.0f;
    float2 X0 = xunp[fold];
    float2 X1 = xunp[512 + fold];
    const bool s0 = (selw[fold >> 5]        >> (fold & 31)) & 1u;
    const bool s1 = (selw[16 + (fold >> 5)] >> (fold & 31)) & 1u;
    float x0i = sgn * X0.y;
    float x1i = sgn * X1.y;
    float Zr = (s0 ? X0.x : 0.f) - (s1 ? x1i : 0.f);
    float Zi = (s0 ? x0i : 0.f) + (s1 ? X1.x : 0.f);
    return float2{ Zr, -Zi };
}

// ---- 1024-pt packed FFT core (16x64 four-step), LDS float2 twiddle table ----
__device__ __forceinline__ void fft1024(const float2* __restrict__ xin,
                                        const float2* __restrict__ twF,
                                        int lane, int w, float* ar, float* ai) {
    float Fr[4][4], Fi[4][4];
#pragma unroll
    for (int n1a = 0; n1a < 4; ++n1a) {
        float2 a  = xin[lane + 64 * (n1a + 0)];
        float2 bb = xin[lane + 64 * (n1a + 4)];
        float2 cV = xin[lane + 64 * (n1a + 8)];
        float2 d  = xin[lane + 64 * (n1a + 12)];
        float t0r = a.x + cV.x, t0i = a.y + cV.y;
        float t1r = a.x - cV.x, t1i = a.y - cV.y;
        float t2r = bb.x + d.x, t2i = bb.y + d.y;
        float t3r = bb.x - d.x, t3i = bb.y - d.y;
        Fr[n1a][0] = t0r + t2r;  Fi[n1a][0] = t0i + t2i;
        Fr[n1a][2] = t0r - t2r;  Fi[n1a][2] = t0i - t2i;
        Fr[n1a][1] = t1r + t3i;  Fi[n1a][1] = t1i - t3r;   // t1 - i*t3
        Fr[n1a][3] = t1r - t3i;  Fi[n1a][3] = t1i + t3r;   // t1 + i*t3
    }
#pragma unroll
    for (int q = 0; q < 4; ++q) {
        const int k1 = (w << 2) | q;
        float cr = Fr[0][q], ci = Fi[0][q];
#pragma unroll
        for (int n1a = 1; n1a < 4; ++n1a) {
            int e = (n1a * k1) & 15;
            float wr = W16RF[e], wi = W16IF[e];
            cr += Fr[n1a][q] * wr - Fi[n1a][q] * wi;
            ci += Fr[n1a][q] * wi + Fi[n1a][q] * wr;
        }
        float2 tw = twF[PAD16((lane * k1) & 1023)];
        ar[q] = cr * tw.x - ci * tw.y;
        ai[q] = cr * tw.y + ci * tw.x;
    }
#pragma unroll
    for (int s = 0; s < 6; ++s) {
        const int half = 32 >> s;
        const int e = (lane & (half - 1)) << s;          // < 32
        float2 tw = twF[PAD16(e << 4)];                  // W64^e = W1024^(16e)
        const bool up = (lane & half) != 0;
#pragma unroll
        for (int q = 0; q < 4; ++q) {
            float orr = __shfl_xor(ar[q], half);
            float oii = __shfl_xor(ai[q], half);
            float sr = ar[q] + orr, si = ai[q] + oii;
            float dr = orr - ar[q], di = oii - ai[q];
            ar[q] = up ? (dr * tw.x - di * tw.y) : sr;
            ai[q] = up ? (dr * tw.y + di * tw.x) : si;
        }
    }
}

// ---- same core, input generated via zval (masked spectrum) ----
__device__ __forceinline__ void fft1024_z(const float2* __restrict__ xunp,
                                          const unsigned* __restrict__ selw,
                                          const float2* __restrict__ twF,
                                          int lane, int w, float* ar, float* ai) {
    float Fr[4][4], Fi[4][4];
#pragma unroll
    for (int n1a = 0; n1a < 4; ++n1a) {
        float2 a  = zval(xunp, selw, lane + 64 * (n1a + 0));
        float2 bb = zval(xunp, selw, lane + 64 * (n1a + 4));
        float2 cV = zval(xunp, selw, lane + 64 * (n1a + 8));
        float2 d  = zval(xunp, selw, lane + 64 * (n1a + 12));
        float t0r = a.x + cV.x, t0i = a.y + cV.y;
        float t1r = a.x - cV.x, t1i = a.y - cV.y;
        float t2r = bb.x + d.x, t2i = bb.y + d.y;
        float t3r = bb.x - d.x, t3i = bb.y - d.y;
        Fr[n1a][0] = t0r + t2r;  Fi[n1a][0] = t0i + t2i;
        Fr[n1a][2] = t0r - t2r;  Fi[n1a][2] = t0i - t2i;
        Fr[n1a][1] = t1r + t3i;  Fi[n1a][1] = t1i - t3r;
        Fr[n1a][3] = t1r - t3i;  Fi[n1a][3] = t1i + t3r;
    }
#pragma unroll
    for (int q = 0; q < 4; ++q) {
        const int k1 = (w << 2) | q;
        float cr = Fr[0][q], ci = Fi[0][q];
#pragma unroll
        for (int n1a = 1; n1a < 4; ++n1a) {
            int e = (n1a * k1) & 15;
            float wr = W16RF[e], wi = W16IF[e];
            cr += Fr[n1a][q] * wr - Fi[n1a][q] * wi;
            ci += Fr[n1a][q] * wi + Fi[n1a][q] * wr;
        }
        float2 tw = twF[PAD16((lane * k1) & 1023)];
        ar[q] = cr * tw.x - ci * tw.y;
        ai[q] = cr * tw.y + ci * tw.x;
    }
#pragma unroll
    for (int s = 0; s < 6; ++s) {
        const int half = 32 >> s;
        const int e = (lane & (half - 1)) << s;
        float2 tw = twF[PAD16(e << 4)];
        const bool up = (lane & half) != 0;
#pragma unroll
        for (int q = 0; q < 4; ++q) {
            float orr = __shfl_xor(ar[q], half);
            float oii = __shfl_xor(ai[q], half);
            float sr = ar[q] + orr, si = ai[q] + oii;
            float dr = orr - ar[q], di = oii - ai[q];
            ar[q] = up ? (dr * tw.x - di * tw.y) : sr;
            ai[q] = up ? (dr * tw.y + di * tw.x) : si;
        }
    }
}

// ---------------- Single fused kernel ----------------
// grid = 1024 blocks (one column-pair each), block = 256 threads = 4 waves.
__global__ void __launch_bounds__(256, 4)
fl_fused_kernel(const float* __restrict__ x, float* __restrict__ out) {
    __shared__ float2 twF[PAD16(1023) + 1];   // fp32 twiddle table (computed in-block)
    __shared__ float2 spP[PAD16(1023) + 1];   // packed spectrum
    __shared__ char smemU[8192];              // union: xsh (FFT1 in) | xunp {X0[512], X1[512]}
    __shared__ int hist[512];                 // 256 bins per column
    __shared__ unsigned selw[32];             // selection bitsets: [c][m>>5], m in 0..511
    float2* xsh  = (float2*)smemU;
    float2* xunp = (float2*)smemU;            // X0 at [0..511], X1 at [512..1023]

    const int tid  = threadIdx.x;
    const int lane = tid & 63;
    const int w    = tid >> 6;

    const int bid = blockIdx.x;
    const int sp  = ((bid & 7) << 7) | (bid >> 3);   // XCD-chunked, bijective over 1024
    const int b   = sp >> 7;
    const int d0  = (sp & 127) << 1;

    // hoist global loads into registers (latency overlaps the sincos below)
    float2 xv[4];
#pragma unroll
    for (int j = 0; j < 4; ++j) {
        int e = tid + (j << 8);
        xv[j] = *reinterpret_cast<const float2*>(&x[(((size_t)(b << 10) + e) << 8) + d0]);
    }
    // quadrant-symmetry twiddles: ONE sincos per thread fills 4 table entries
    {
        float sn, cs;
        __sincosf((float)tid * C1024F, &sn, &cs);
        twF[PAD16(tid)]       = float2{  cs, -sn };
        twF[PAD16(tid + 256)] = float2{ -sn, -cs };
        twF[PAD16(tid + 512)] = float2{ -cs,  sn };
        twF[PAD16(tid + 768)] = float2{  sn,  cs };
    }
#pragma unroll
    for (int j = 0; j < 4; ++j) xsh[tid + (j << 8)] = xv[j];
    if (tid < 32) selw[tid] = 0u;
    __syncthreads();                                   // barrier 1

    // ---- FFT 1: forward transform of packed pair
    float ar[4], ai[4];
    fft1024(xsh, twF, lane, w, ar, ai);

    const int krev = (int)(__brev((unsigned)lane) >> 26);  // rev6(lane)
#pragma unroll
    for (int q = 0; q < 4; ++q) {
        int k = ((w << 2) | q) + (krev << 4);
        spP[PAD16(k)] = float2{ ar[q], ai[q] };
    }
    __syncthreads();                                   // barrier 2

    // ---- divergent phase: waves 0,1 do top-k; waves 2,3 unpack X0/X1 into xunp
    if (tid < 128) {
        const int c = tid >> 6;
        int* histc = hist + (c << 8);

        // magnitudes directly from the packed spectrum
        float v[8]; int hiw[8];
#pragma unroll
        for (int q = 0; q < 8; ++q) {
            int m = (q << 6) | lane;
            int n = (1024 - m) & 1023;
            float2 Pk = spP[PAD16(m)];
            float2 Pn = spP[PAD16(n)];
            float rr, ii;
            if (c == 0) { rr = 0.5f * (Pk.x + Pn.x); ii = 0.5f * (Pk.y - Pn.y); }
            else        { rr = 0.5f * (Pk.y + Pn.y); ii = 0.5f * (Pn.x - Pk.x); }
            v[q] = rr * rr + ii * ii;
        }
        if (lane == 0) v[0] = -1.0f;   // exclude m=0; m=512 excluded by range
#pragma unroll
        for (int q = 0; q < 8; ++q) hiw[q] = __float_as_int(v[q]);

        int mx = hiw[0];
#pragma unroll
        for (int q = 1; q < 8; ++q) mx = max(mx, hiw[q]);
#pragma unroll
        for (int off = 1; off < 64; off <<= 1) mx = max(mx, __shfl_xor(mx, off));

        const int base = (mx >> 20) - 250;
        int idx[8];
#pragma unroll
        for (int q = 0; q < 8; ++q) {
            int t = (hiw[q] >> 20) - base;
            idx[q] = t < 0 ? 0 : t;
        }

        *reinterpret_cast<int4*>(&histc[lane << 2]) = int4{0, 0, 0, 0};
#pragma unroll
        for (int q = 0; q < 8; ++q) atomicAdd(&histc[idx[q]], 1);

        int4 cc = *reinterpret_cast<int4*>(&histc[lane << 2]);
        int s_local = cc.x + cc.y + cc.z + cc.w;

        int s = s_local;
#pragma unroll
        for (int off = 1; off < 64; off <<= 1) {
            int t = __shfl_down(s, off);
            if (lane + off < 64) s += t;
        }
        const int S_gt = s - s_local;
        const int A3 = S_gt;
        const int A2 = A3 + cc.w;
        const int A1 = A2 + cc.z;
        const int A0 = A1 + cc.y;

        int foundB = -1, foundR = 0;
        if (A0 < KSEL && A0 + cc.x >= KSEL) { foundB = (lane << 2) | 0; foundR = KSEL - A0; }
        if (A1 < KSEL && A1 + cc.y >= KSEL) { foundB = (lane << 2) | 1; foundR = KSEL - A1; }
        if (A2 < KSEL && A2 + cc.z >= KSEL) { foundB = (lane << 2) | 2; foundR = KSEL - A2; }
        if (A3 < KSEL && A3 + cc.w >= KSEL) { foundB = (lane << 2) | 3; foundR = KSEL - A3; }

        unsigned long long fm = __ballot(foundB >= 0);
        const int srcB = (int)(__ffsll((unsigned long long)fm) - 1);
        int B = __shfl(foundB, srcB);
        int r = __shfl(foundR, srcB);

        unsigned selmask = 0, candmask = 0;
#pragma unroll
        for (int q = 0; q < 8; ++q) {
            if (idx[q] > B) selmask |= (1u << q);
            else if (idx[q] == B) candmask |= (1u << q);
        }

        // second-level histogram on mantissa bits 12..19 (valid when B>0)
        if (r > 0 && B > 0) {
            *reinterpret_cast<int4*>(&histc[lane << 2]) = int4{0, 0, 0, 0};
            int idx2[8];
#pragma unroll
            for (int q = 0; q < 8; ++q) {
                idx2[q] = (hiw[q] >> 12) & 255;
                if ((candmask >> q) & 1u) atomicAdd(&histc[idx2[q]], 1);
            }
            int4 c2 = *reinterpret_cast<int4*>(&histc[lane << 2]);
            int s2l = c2.x + c2.y + c2.z + c2.w;
            int ss = s2l;
#pragma unroll
            for (int off = 1; off < 64; off <<= 1) {
                int t = __shfl_down(ss, off);
                if (lane + off < 64) ss += t;
            }
            const int G3 = ss - s2l;
            const int G2 = G3 + c2.w;
            const int G1 = G2 + c2.z;
            const int G0 = G1 + c2.y;
            int fB2 = -1, fR2 = 0;
            if (G0 < r && G0 + c2.x >= r) { fB2 = (lane << 2) | 0; fR2 = r - G0; }
            if (G1 < r && G1 + c2.y >= r) { fB2 = (lane << 2) | 1; fR2 = r - G1; }
            if (G2 < r && G2 + c2.z >= r) { fB2 = (lane << 2) | 2; fR2 = r - G2; }
            if (G3 < r && G3 + c2.w >= r) { fB2 = (lane << 2) | 3; fR2 = r - G3; }
            unsigned long long fm2 = __ballot(fB2 >= 0);
            const int src2 = (int)(__ffsll((unsigned long long)fm2) - 1);
            const int Bb = __shfl(fB2, src2);
            const int rr = __shfl(fR2, src2);
            unsigned newcand = 0;
#pragma unroll
            for (int q = 0; q < 8; ++q) {
                if ((candmask >> q) & 1u) {
                    if (idx2[q] > Bb) selmask |= (1u << q);
                    else if (idx2[q] == Bb) newcand |= (1u << q);
                }
            }
            candmask = newcand;
            r = rr;
        }

        for (int it = 0; it < r; ++it) {
            float bv = -2.0f; int bq = -1;
#pragma unroll
            for (int q = 0; q < 8; ++q) {
                bool cand = ((candmask >> q) & 1u) != 0;
                if (cand && v[q] > bv) { bv = v[q]; bq = q; }
            }
            int bi = (bq < 0) ? 0x7FFFFFFF : ((bq << 6) | lane);
#pragma unroll
            for (int off = 1; off < 64; off <<= 1) {
                float ov = __shfl_xor(bv, off);
                int   oi = __shfl_xor(bi, off);
                if (ov > bv || (ov == bv && oi < bi)) { bv = ov; bi = oi; }
            }
            if (bi != 0x7FFFFFFF && lane == (bi & 63)) {
                unsigned bit = 1u << (bi >> 6);
                selmask  |= bit;
                candmask &= ~bit;
            }
        }

        // ---- fp64 refinement when the rank-32/33 fp32 gap is too small.
        {
            float vminS = 3.0e38f, vmaxU = -3.0e38f;
#pragma unroll
            for (int q = 0; q < 8; ++q) {
                if ((selmask >> q) & 1u) vminS = fminf(vminS, v[q]);
                else                     vmaxU = fmaxf(vmaxU, v[q]);
            }
#pragma unroll
            for (int off = 1; off < 64; off <<= 1) {
                vminS = fminf(vminS, __shfl_xor(vminS, off));
                vmaxU = fmaxf(vmaxU, __shfl_xor(vmaxU, off));
            }
            const float tau = RTAU * vminS;
            if (vminS - vmaxU < tau) {            // wave-uniform, rare
                const float lo = vmaxU - tau, hi = vminS + tau;
                unsigned candq = 0; int nAbove = 0;
#pragma unroll
                for (int q = 0; q < 8; ++q) {
                    bool inw = (v[q] >= lo) && (v[q] <= hi);
                    if (inw) candq |= (1u << q);
                    if (((selmask >> q) & 1u) && v[q] > hi) ++nAbove;
                }
#pragma unroll
                for (int off = 1; off < 64; off <<= 1) nAbove += __shfl_xor(nAbove, off);
                const int kneed = KSEL - nAbove;
                selmask &= ~candq;

                const float* xcol = x + ((size_t)(b << 10) << 8) + d0 + c;
                double sV = -1.0; int sSrc = 0; int cnum = 0;
                for (int q = 0; q < 8; ++q) {
                    unsigned long long bal = __ballot((candq >> q) & 1u);
                    while (bal) {
                        int srcl = (int)(__ffsll(bal) - 1);
                        bal &= bal - 1;
                        int m = (q << 6) | srcl;
                        double th0 = (double)((m * lane) & 1023)
                                   * (-6.283185307179586476925286766559 / 1024.0);
                        double wr, wi;
                        { double s0, c0; sincos(th0, &s0, &c0); wr = c0; wi = s0; }
                        const double stR = W16R_[m & 15], stI = W16I_[m & 15];
                        double sr = 0.0, si = 0.0;
#pragma unroll
                        for (int u = 0; u < 16; ++u) {
                            int n = lane + (u << 6);
                            double xvd = (double)xcol[(size_t)n << 8];
                            sr = fma(xvd, wr, sr);
                            si = fma(xvd, wi, si);
                            double nwr = wr * stR - wi * stI;
                            double nwi = wr * stI + wi * stR;
                            wr = nwr; wi = nwi;
                        }
#pragma unroll
                        for (int off = 1; off < 64; off <<= 1) {
                            sr += __shfl_xor(sr, off);
                            si += __shfl_xor(si, off);
                        }
                        if (lane == cnum) { sV = sr * sr + si * si; sSrc = (q << 6) | srcl; }
                        ++cnum;
                        if (cnum >= 64) break;
                    }
                    if (cnum >= 64) break;
                }
                for (int it = 0; it < kneed; ++it) {
                    double bv = sV; int bl = lane;
#pragma unroll
                    for (int off = 1; off < 64; off <<= 1) {
                        double ov = __shfl_xor(bv, off);
                        int    ol = __shfl_xor(bl, off);
                        if (ov > bv || (ov == bv && ol < bl)) { bv = ov; bl = ol; }
                    }
                    int wsrc = __shfl(sSrc, bl);
                    if (lane == (wsrc & 63)) selmask |= 1u << (wsrc >> 6);
                    if (lane == bl) sV = -2.0;
                }
            }
        }

        // ---- write selection bits (m only; mirror derived at read time)
#pragma unroll
        for (int q = 0; q < 8; ++q) {
            if ((selmask >> q) & 1u) {
                int m = (q << 6) | lane;           // 1..511
                atomicOr(&selw[(c << 4) | (m >> 5)], 1u << (m & 31));
            }
        }
    } else {
        // waves 2,3: Hermitian unpack spP -> X0[k], X1[k] (k = 0..511) in xunp
        const int t2 = tid - 128;                  // 0..127
#pragma unroll
        for (int j = 0; j < 4; ++j) {
            int k = t2 + (j << 7);                 // 0..511
            int n = (1024 - k) & 1023;
            float2 Pk = spP[PAD16(k)];
            float2 Pn = spP[PAD16(n)];
            xunp[k]       = float2{ 0.5f * (Pk.x + Pn.x), 0.5f * (Pk.y - Pn.y) };   // X0[k]
            xunp[512 + k] = float2{ 0.5f * (Pk.y + Pn.y), 0.5f * (Pn.x - Pk.x) };   // X1[k]
        }
    }
    __syncthreads();                                   // barrier 3

    // ---- FFT 2 (inverse via conjugation), masked spectrum generated on the fly
    fft1024_z(xunp, selw, twF, lane, w, ar, ai);

    // ---- write y: out0 = Re(R)/1024, out1 = -Im(R)/1024; duplicate t<256 to t+1024
    {
        const float S = 1.0f / 1024.0f;
        float2* o2 = reinterpret_cast<float2*>(out + (size_t)b * OUT_T * DM + d0);
#pragma unroll
        for (int q = 0; q < 4; ++q) {
            int t = ((w << 2) | q) + (krev << 4);
            float2 o{ ar[q] * S, -ai[q] * S };
            o2[(size_t)t * 128] = o;
            if (t < PRED_LEN) o2[(size_t)(t + T_LEN) * 128] = o;
        }
    }
}

extern "C" void kernel_launch(void* const* d_in, const int* in_sizes, int n_in,
                              void* d_out, int out_size, void* d_ws, size_t ws_size,
                              hipStream_t stream) {
    const float* x = (const float*)d_in[0];
    float* out = (float*)d_out;
    hipLaunchKernelGGL(fl_fused_kernel, dim3(1024), dim3(256), 0, stream, x, out);
}